// Round 8
// baseline (92.747 us; speedup 1.0000x reference)
//
#include <hip/hip_runtime.h>
#include <hip/hip_bf16.h>

typedef __attribute__((ext_vector_type(8)))  short short8;
typedef __attribute__((ext_vector_type(16))) float f32x16;

#define DIM_D 256
#define DIM_O 256
#define DIM_K 8
#define BM 64
#define DCHUNK 16
#define NCHUNK (DIM_D / DCHUNK)   // 16
#define LDSROW 144                // shorts per row = 288 B (16 slots*8 + pad)

__device__ __forceinline__ unsigned short f2bf(float f) {
    union { float f; unsigned int u; } v; v.f = f;
    unsigned int u = v.u;
    u += 0x7fffu + ((u >> 16) & 1u);   // round-to-nearest-even
    return (unsigned short)(u >> 16);
}

// v_cvt_pk_bf16_f32: dst.lo = bf16(lo), dst.hi = bf16(hi), RNE — 1 instr
__device__ __forceinline__ unsigned int cvt_pk_bf16(float lo, float hi) {
    unsigned int r;
    asm("v_cvt_pk_bf16_f32 %0, %1, %2" : "=v"(r) : "v"(lo), "v"(hi));
    return r;
}

// Pack cheby_coeffs (O,D,K) f32 -> bf16 in 32x32x16 MFMA B-fragment order:
// wp[s][ct][lane][j] = c[o = ct*32 + (l&31)][d = s*2 + (l>>5)][k = j]
// (B-frag: col = lane&31, k = (lane>>5)*8 + j; our K-axis = d*8 + order)
__global__ void pack_w_kernel(const float* __restrict__ coeffs,
                              unsigned short* __restrict__ wp) {
    int e = blockIdx.x * 256 + threadIdx.x;      // 0 .. 524287
    int j  = e & 7;
    int l  = (e >> 3) & 63;
    int ct = (e >> 9) & 7;
    int s  = e >> 12;                            // 0..127
    int o = ct * 32 + (l & 31);
    int d = s * 2 + (l >> 5);
    wp[e] = f2bf(coeffs[((size_t)o * DIM_D + d) * DIM_K + j]);
}

// tanh + Chebyshev recurrence + packed-bf16 + LDS write for ONE (row,d):
// one short8 = T0..T7 = exactly one 32x32x16 A-fragment k-half.
__device__ __forceinline__ void cheb_store(float xs, unsigned short* dst) {
    // tanh(x) = 1 - 2/(e^{2x}+1); |x| <= ~6 for randn inputs, no clamp
    float e2 = __expf(2.f * xs);
    float r  = __builtin_amdgcn_rcpf(e2 + 1.f);
    float T1 = __builtin_fmaf(-2.f, r, 1.f);
    float tx = T1 + T1;
    float T2 = __builtin_fmaf(tx, T1, -1.f);
    float T3 = __builtin_fmaf(tx, T2, -T1);
    float T4 = __builtin_fmaf(tx, T3, -T2);
    float T5 = __builtin_fmaf(tx, T4, -T3);
    float T6 = __builtin_fmaf(tx, T5, -T4);
    float T7 = __builtin_fmaf(tx, T6, -T5);
    union { unsigned int u[4]; short8 s; } tv;
    tv.u[0] = cvt_pk_bf16(1.f, T1);
    tv.u[1] = cvt_pk_bf16(T2, T3);
    tv.u[2] = cvt_pk_bf16(T4, T5);
    tv.u[3] = cvt_pk_bf16(T6, T7);
    *(short8*)dst = tv.s;
}

__global__ __launch_bounds__(256, 4) void cfkan_kernel(
    const float* __restrict__ x,
    const unsigned short* __restrict__ wp,
    const float* __restrict__ bias,
    float* __restrict__ y)
{
    // double-buffered A tile; 288 B row stride (bank-spread), slot XOR-swizzle
    __shared__ unsigned short Abuf[2][BM][LDSROW];

    const int t = threadIdx.x;
    const int w = t >> 6;            // wave 0..3 -> output cols [64w, 64w+64)
    const int l = t & 63;
    const int m = l & 31;            // row (A) / col (B,C) within 32-tile
    const int h = l >> 5;            // k-half
    const int row0 = blockIdx.x * BM;
    const short8* wp8 = (const short8*)wp;

    f32x16 acc[2][2];
    #pragma unroll
    for (int rt = 0; rt < 2; ++rt)
        #pragma unroll
        for (int ct = 0; ct < 2; ++ct)
            #pragma unroll
            for (int q = 0; q < 16; ++q)
                acc[rt][ct][q] = 0.f;

    const int lrow  = t >> 2;        // 0..63 (row this thread stages)
    const int dpart = (t & 3) * 4;   // which 4 of the 16 chunk-d's
    const float* xrow = x + (size_t)(row0 + lrow) * DIM_D + dpart;

// A-frag read: lane l -> row rt*32+m, d-slot (2*SL + h), swizzled by row&15(=m&15)
#define RSLOT(SL) ((((2 * (SL) + h) ^ (m & 15))) * 8)
#define READ2(DST, AB, SL) do {                                            \
    DST[0] = *(const short8*)&AB[m][RSLOT(SL)];                            \
    DST[1] = *(const short8*)&AB[32 + m][RSLOT(SL)];                       \
} while (0)
#define WSLOT(P) ((((dpart + (P)) ^ (lrow & 15))) * 8)

    // ---- prologue: stage chunk 0; preload x(chunk1) + B(step0) ----
    {
        float4 a = *(const float4*)xrow;
        float xs[4] = {a.x, a.y, a.z, a.w};
        #pragma unroll
        for (int p = 0; p < 4; ++p)
            cheb_store(xs[p], &Abuf[0][lrow][WSLOT(p)]);
    }
    float4 xv = *(const float4*)(xrow + DCHUNK);
    short8 bc[2], bn[2];
    bc[0] = wp8[(0 * 8 + w * 2 + 0) * 64 + l];
    bc[1] = wp8[(0 * 8 + w * 2 + 1) * 64 + l];
    __syncthreads();
    short8 r[2], rn[2];
    READ2(r, Abuf[0], 0);

    // ---- main loop: 8 steps/chunk, per-step fine interleave, 1 barrier ----
    #pragma unroll 1
    for (int c = 0; c < NCHUNK; ++c) {
        const unsigned short (*A)[LDSROW]   = Abuf[c & 1];
        unsigned short (*ANX)[LDSROW]       = Abuf[(c & 1) ^ 1];
        const int sg0 = c * 8;
        const int sn  = (c + 2 < NCHUNK) ? c + 2 : NCHUNK - 1;
        const bool stage = (c < NCHUNK - 1);
        float4 xn = *(const float4*)(xrow + sn * DCHUNK);
        float xs[4] = {xv.x, xv.y, xv.z, xv.w};

        #pragma unroll
        for (int sl = 0; sl < 8; ++sl) {
            // prefetch next step's B fragments (wraps at end; harmless)
            const int sgn = (sg0 + sl + 1) & 127;
            bn[0] = wp8[(sgn * 8 + w * 2 + 0) * 64 + l];
            bn[1] = wp8[(sgn * 8 + w * 2 + 1) * 64 + l];
            // prefetch next step's A fragments (within chunk)
            if (sl < 7) READ2(rn, A, sl + 1);

            __builtin_amdgcn_s_setprio(1);
            acc[0][0] = __builtin_amdgcn_mfma_f32_32x32x16_bf16(
                r[0], bc[0], acc[0][0], 0, 0, 0);
            acc[0][1] = __builtin_amdgcn_mfma_f32_32x32x16_bf16(
                r[0], bc[1], acc[0][1], 0, 0, 0);
            acc[1][0] = __builtin_amdgcn_mfma_f32_32x32x16_bf16(
                r[1], bc[0], acc[1][0], 0, 0, 0);
            acc[1][1] = __builtin_amdgcn_mfma_f32_32x32x16_bf16(
                r[1], bc[1], acc[1][1], 0, 0, 0);
            __builtin_amdgcn_s_setprio(0);

            // one cheb-stage on even steps (4 per chunk, spread out)
            if (!(sl & 1) && stage)
                cheb_store(xs[sl >> 1], &ANX[lrow][WSLOT(sl >> 1)]);

            if (sl < 7) { r[0] = rn[0]; r[1] = rn[1]; }
            bc[0] = bn[0]; bc[1] = bn[1];
        }
        xv = xn;
        __syncthreads();
        // prefetch next chunk's step-0 fragments (cross-barrier)
        if (c < NCHUNK - 1) READ2(r, ANX, 0);
    }

    // ---- epilogue: add bias, store f32 ----
    // C/D 32x32: col = lane&31, row = (q&3) + 8*(q>>2) + 4*(lane>>5)
    #pragma unroll
    for (int ct = 0; ct < 2; ++ct) {
        const int col = w * 64 + ct * 32 + m;
        const float bv = bias[col];
        #pragma unroll
        for (int rt = 0; rt < 2; ++rt) {
            #pragma unroll
            for (int q = 0; q < 16; ++q) {
                const int grow = row0 + rt * 32 + (q & 3) + 8 * (q >> 2) + 4 * h;
                y[(size_t)grow * DIM_O + col] = acc[rt][ct][q] + bv;
            }
        }
    }
#undef RSLOT
#undef READ2
#undef WSLOT
}

extern "C" void kernel_launch(void* const* d_in, const int* in_sizes, int n_in,
                              void* d_out, int out_size, void* d_ws, size_t ws_size,
                              hipStream_t stream) {
    const float* x      = (const float*)d_in[0];
    const float* coeffs = (const float*)d_in[1];
    const float* bias   = (const float*)d_in[2];
    float* y = (float*)d_out;
    unsigned short* wp = (unsigned short*)d_ws;   // 2048*256 bf16 = 1 MB

    const int n_tokens = in_sizes[0] / DIM_D;     // 65536

    pack_w_kernel<<<(DIM_O * DIM_D * DIM_K) / 256, 256, 0, stream>>>(coeffs, wp);
    cfkan_kernel<<<n_tokens / BM, 256, 0, stream>>>(x, wp, bias, y);
}

// Round 9
// 75.272 us; speedup vs baseline: 1.2322x; 1.2322x over previous
//
#include <hip/hip_runtime.h>
#include <hip/hip_bf16.h>

typedef __attribute__((ext_vector_type(8)))  short short8;
typedef __attribute__((ext_vector_type(16))) float f32x16;

#define DIM_D 256
#define DIM_O 256
#define DIM_K 8
#define BM 128
#define DCHUNK 16
#define NCHUNK (DIM_D / DCHUNK)   // 16
#define LDSROW 144                // shorts per row = 288 B (16 slots*8 + pad)

__device__ __forceinline__ unsigned short f2bf(float f) {
    union { float f; unsigned int u; } v; v.f = f;
    unsigned int u = v.u;
    u += 0x7fffu + ((u >> 16) & 1u);   // round-to-nearest-even
    return (unsigned short)(u >> 16);
}

// v_cvt_pk_bf16_f32: dst.lo = bf16(lo), dst.hi = bf16(hi), RNE — 1 instr
__device__ __forceinline__ unsigned int cvt_pk_bf16(float lo, float hi) {
    unsigned int r;
    asm("v_cvt_pk_bf16_f32 %0, %1, %2" : "=v"(r) : "v"(lo), "v"(hi));
    return r;
}

// Pack cheby_coeffs (O,D,K) f32 -> bf16 in 32x32x16 MFMA B-fragment order:
// wp[s][ct][lane][j] = c[o = ct*32 + (l&31)][d = s*2 + (l>>5)][k = j]
// (B-frag: col = lane&31, k = (lane>>5)*8 + j; our K-axis = d*8 + order)
__global__ void pack_w_kernel(const float* __restrict__ coeffs,
                              unsigned short* __restrict__ wp) {
    int e = blockIdx.x * 256 + threadIdx.x;      // 0 .. 524287
    int j  = e & 7;
    int l  = (e >> 3) & 63;
    int ct = (e >> 9) & 7;
    int s  = e >> 12;                            // 0..127
    int o = ct * 32 + (l & 31);
    int d = s * 2 + (l >> 5);
    wp[e] = f2bf(coeffs[((size_t)o * DIM_D + d) * DIM_K + j]);
}

// tanh + Chebyshev recurrence + packed-bf16 + LDS write for ONE (row,d):
// one short8 = T0..T7 = exactly one 32x32x16 A-fragment k-half.
__device__ __forceinline__ void cheb_store(float xs, unsigned short* dst) {
    // tanh(x) = 1 - 2/(e^{2x}+1); |x| <= ~6 for randn inputs, no clamp
    float e2 = __expf(2.f * xs);
    float r  = __builtin_amdgcn_rcpf(e2 + 1.f);
    float T1 = __builtin_fmaf(-2.f, r, 1.f);
    float tx = T1 + T1;
    float T2 = __builtin_fmaf(tx, T1, -1.f);
    float T3 = __builtin_fmaf(tx, T2, -T1);
    float T4 = __builtin_fmaf(tx, T3, -T2);
    float T5 = __builtin_fmaf(tx, T4, -T3);
    float T6 = __builtin_fmaf(tx, T5, -T4);
    float T7 = __builtin_fmaf(tx, T6, -T5);
    union { unsigned int u[4]; short8 s; } tv;
    tv.u[0] = cvt_pk_bf16(1.f, T1);
    tv.u[1] = cvt_pk_bf16(T2, T3);
    tv.u[2] = cvt_pk_bf16(T4, T5);
    tv.u[3] = cvt_pk_bf16(T6, T7);
    *(short8*)dst = tv.s;
}

__global__ __launch_bounds__(256, 2) void cfkan_kernel(
    const float* __restrict__ x,
    const unsigned short* __restrict__ wp,
    const float* __restrict__ bias,
    float* __restrict__ y)
{
    // double-buffered A tile; 288 B row stride, slot XOR-swizzle; 72 KB
    __shared__ unsigned short Abuf[2][BM][LDSROW];

    const int t = threadIdx.x;
    const int w = t >> 6;            // wave 0..3 -> output cols [64w, 64w+64)
    const int l = t & 63;
    const int m = l & 31;            // row (A) / col (B,C) within 32-tile
    const int h = l >> 5;            // k-half
    const int row0 = blockIdx.x * BM;
    const short8* wp8 = (const short8*)wp;

    f32x16 acc[4][2];
    #pragma unroll
    for (int rt = 0; rt < 4; ++rt)
        #pragma unroll
        for (int ct = 0; ct < 2; ++ct)
            #pragma unroll
            for (int q = 0; q < 16; ++q)
                acc[rt][ct][q] = 0.f;

    const int lrow  = t >> 1;        // 0..127 (row this thread stages)
    const int dpart = (t & 1) * 8;   // which 8 of the 16 chunk-d's
    const float* xrow = x + (size_t)(row0 + lrow) * DIM_D + dpart;

// A-frag read: lane l -> rows rt*32+m, d-slot (2*S + h), XOR-swizzled
#define RSLOT(S) ((((2 * (S) + h) ^ (m & 15))) * 8)
#define READA(DST, AB, S) do {                                             \
    DST[0] = *(const short8*)&AB[      m][RSLOT(S)];                       \
    DST[1] = *(const short8*)&AB[ 32 + m][RSLOT(S)];                       \
    DST[2] = *(const short8*)&AB[ 64 + m][RSLOT(S)];                       \
    DST[3] = *(const short8*)&AB[ 96 + m][RSLOT(S)];                       \
} while (0)
#define WSLOT(P) ((((dpart + (P)) ^ (lrow & 15))) * 8)
#define LOADB2(DST, SG) do {                                               \
    DST[0] = wp8[((SG) * 8 + w * 2 + 0) * 64 + l];                         \
    DST[1] = wp8[((SG) * 8 + w * 2 + 1) * 64 + l];                         \
} while (0)
// barrier that drains ONLY LDS ops; global loads stay in flight (T4)
#define SOFT_BARRIER() do {                                                \
    asm volatile("s_waitcnt lgkmcnt(0)" ::: "memory");                     \
    __builtin_amdgcn_s_barrier();                                          \
    __builtin_amdgcn_sched_barrier(0);                                     \
} while (0)

    // ---- prologue: stage chunk 0; preload x(chunk1) + B(step0) ----
    float xv[8];
    {
        float4 a0 = *(const float4*)xrow;
        float4 a1 = *(const float4*)(xrow + 4);
        float xs[8] = {a0.x, a0.y, a0.z, a0.w, a1.x, a1.y, a1.z, a1.w};
        #pragma unroll
        for (int p = 0; p < 8; ++p)
            cheb_store(xs[p], &Abuf[0][lrow][WSLOT(p)]);
        float4 b0 = *(const float4*)(xrow + DCHUNK);
        float4 b1 = *(const float4*)(xrow + DCHUNK + 4);
        xv[0] = b0.x; xv[1] = b0.y; xv[2] = b0.z; xv[3] = b0.w;
        xv[4] = b1.x; xv[5] = b1.y; xv[6] = b1.z; xv[7] = b1.w;
    }
    short8 bc[2], bn[2];
    LOADB2(bc, 0);
    SOFT_BARRIER();
    short8 r[4], rn[4];
    READA(r, Abuf[0], 0);

    // ---- main loop: 8 k-steps/chunk, fine interleave, soft barrier ----
    #pragma unroll 1
    for (int c = 0; c < NCHUNK; ++c) {
        const unsigned short (*A)[LDSROW] = Abuf[c & 1];
        unsigned short (*ANX)[LDSROW]     = Abuf[(c & 1) ^ 1];
        const int sg0 = c * 8;
        const int sn  = (c + 2 < NCHUNK) ? c + 2 : NCHUNK - 1;
        const bool stage = (c < NCHUNK - 1);
        float4 xn0 = *(const float4*)(xrow + sn * DCHUNK);
        float4 xn1 = *(const float4*)(xrow + sn * DCHUNK + 4);

        #pragma unroll
        for (int s = 0; s < 8; ++s) {
            LOADB2(bn, (sg0 + s + 1) & 127);   // wraps at end; harmless
            if (s < 7) READA(rn, A, s + 1);

            __builtin_amdgcn_s_setprio(1);
            #pragma unroll
            for (int rt = 0; rt < 4; ++rt) {
                acc[rt][0] = __builtin_amdgcn_mfma_f32_32x32x16_bf16(
                    r[rt], bc[0], acc[rt][0], 0, 0, 0);
                acc[rt][1] = __builtin_amdgcn_mfma_f32_32x32x16_bf16(
                    r[rt], bc[1], acc[rt][1], 0, 0, 0);
            }
            __builtin_amdgcn_s_setprio(0);

            if (stage) cheb_store(xv[s], &ANX[lrow][WSLOT(s)]);

            if (s < 7) { r[0] = rn[0]; r[1] = rn[1]; r[2] = rn[2]; r[3] = rn[3]; }
            bc[0] = bn[0]; bc[1] = bn[1];
        }
        xv[0] = xn0.x; xv[1] = xn0.y; xv[2] = xn0.z; xv[3] = xn0.w;
        xv[4] = xn1.x; xv[5] = xn1.y; xv[6] = xn1.z; xv[7] = xn1.w;

        SOFT_BARRIER();
        if (c < NCHUNK - 1) READA(r, ANX, 0);  // next chunk's step-0 frags
    }

    // ---- epilogue: add bias, store f32 ----
    // C/D 32x32: col = lane&31, row = (q&3) + 8*(q>>2) + 4*(lane>>5)
    #pragma unroll
    for (int ct = 0; ct < 2; ++ct) {
        const int col = w * 64 + ct * 32 + m;
        const float bv = bias[col];
        #pragma unroll
        for (int rt = 0; rt < 4; ++rt) {
            #pragma unroll
            for (int q = 0; q < 16; ++q) {
                const int grow = row0 + rt * 32 + (q & 3) + 8 * (q >> 2) + 4 * h;
                y[(size_t)grow * DIM_O + col] = acc[rt][ct][q] + bv;
            }
        }
    }
#undef RSLOT
#undef READA
#undef WSLOT
#undef LOADB2
#undef SOFT_BARRIER
}

extern "C" void kernel_launch(void* const* d_in, const int* in_sizes, int n_in,
                              void* d_out, int out_size, void* d_ws, size_t ws_size,
                              hipStream_t stream) {
    const float* x      = (const float*)d_in[0];
    const float* coeffs = (const float*)d_in[1];
    const float* bias   = (const float*)d_in[2];
    float* y = (float*)d_out;
    unsigned short* wp = (unsigned short*)d_ws;   // 2048*256 bf16 = 1 MB

    const int n_tokens = in_sizes[0] / DIM_D;     // 65536

    pack_w_kernel<<<(DIM_O * DIM_D * DIM_K) / 256, 256, 0, stream>>>(coeffs, wp);
    cfkan_kernel<<<n_tokens / BM, 256, 0, stream>>>(x, wp, bias, y);
}